// Round 14
// baseline (172.525 us; speedup 1.0000x reference)
//
#include <hip/hip_runtime.h>
#include <cstddef>
#include <cstdint>

#define N_NODES 100000
#define IN_CH 256
#define OUT_CH 64
#define N_EDGES 3200000

// bucketing: 128 nodes per bucket, fixed-capacity slots
#define BKT_SHIFT 7
#define BKT_R     128
#define K_BKT     782                 // ceil(100000/128)
#define BKT_CAP   6144                // mean 4096 + 32 sigma; slots of 24KB
#define T_PART    4096                // edges per partition block (smaller => more blocks, occupancy)
#define NBLK_PART ((N_EDGES + T_PART - 1) / T_PART)   // 782
#define NBLK_GEMM 512
#define N_TILES   (N_NODES / 16)      // 6250

// ---- ws layout (bytes) ----
#define WS_FLAG_OFF   0
#define WS_GCNT_OFF   64              // 782 u32 bucket fill counts
#define WS_DINV_OFF   4096            // 400000 B
#define WS_NSE_OFF    404096          // 100000 uint2 = 800000 B
#define WS_EDG_OFF    1204224         // 782*6144*4 = 19,218,432 B (pairs -> sorted src)
#define WS_H_OFF      20422656        // bf16 h: 100000*64*2 = 12.8MB (unscaled)
#define WS_NEED       33222656

// ---- fallback (atomic) layout ----
#define WSF_DEG_OFF   4096
#define WSF_DINV_OFF  404096
#define WSF_H_OFF     804096

typedef __attribute__((ext_vector_type(8))) short bshort8;
typedef __attribute__((ext_vector_type(4))) float f32x4;
typedef __attribute__((ext_vector_type(2))) float f32x2;
typedef __attribute__((ext_vector_type(4))) unsigned u32x4;

// ---------------------------------------------------------------------------
static __device__ __forceinline__ unsigned short f2bf(float f) {
    unsigned u = __builtin_bit_cast(unsigned, f);
    u += 0x7FFFu + ((u >> 16) & 1u);     // RNE (finite inputs)
    return (unsigned short)(u >> 16);
}
static __device__ __forceinline__ float bflo(unsigned u) {
    return __builtin_bit_cast(float, u << 16);
}
static __device__ __forceinline__ float bfhi(unsigned u) {
    return __builtin_bit_cast(float, u & 0xFFFF0000u);
}
static __device__ __forceinline__ f32x2 up2(unsigned u) {
    f32x2 r;
    r.x = __builtin_bit_cast(float, u << 16);
    r.y = __builtin_bit_cast(float, u & 0xFFFF0000u);
    return r;
}

// ---------------------------------------------------------------------------
// probe: detect int64 vs int32 edge layout AND zero the gcnt counters.
__global__ void probe_kernel(const unsigned* __restrict__ ei, int* __restrict__ flag,
                             unsigned* __restrict__ gcnt) {
    if (blockIdx.x == 0) {
        for (int k = threadIdx.x; k < K_BKT; k += 64) gcnt[k] = 0u;
        if (threadIdx.x == 0) {
            int all0 = 1;
            for (int i = 0; i < 16; ++i) all0 &= (ei[2 * i + 1] == 0u);
            *flag = all0;  // 1 => int64 layout, 0 => int32 layout
        }
    }
}

__device__ __forceinline__ int load_idx(const int* ei32, const long long* ei64,
                                        bool is64, long long pos) {
    return is64 ? (int)ei64[pos] : ei32[pos];
}

// ---------------------------------------------------------------------------
// Shared gemm body (256 threads, 4 waves): h = x @ W, bf16 store, UNSCALED.
// (round-9..13-proven code, unchanged)
static __device__ __forceinline__ void gemm_body(char* smem, int gbid, int nblk,
                                                 const float* __restrict__ x,
                                                 const float* __restrict__ W,
                                                 unsigned short* __restrict__ hs) {
    unsigned short (*Wf)[4][64][8] = (unsigned short (*)[4][64][8])smem;
    const int tid = threadIdx.x;
    const int lane = tid & 63;
    const int wv = tid >> 6;           // 4 waves

    for (int i = tid; i < 8 * 4 * 64 * 8; i += 256) {
        int kt = i >> 11;
        int rem = i & 2047;
        int ct = rem >> 9;
        int rem2 = rem & 511;
        int l = rem2 >> 3;
        int j = rem2 & 7;
        int kk = kt * 32 + (l >> 4) * 8 + j;
        int cc = ct * 16 + (l & 15);
        ((unsigned short*)Wf)[i] = f2bf(W[(size_t)kk * OUT_CH + cc]);
    }
    __syncthreads();

    const int r16 = lane & 15;   // A row within tile
    const int q = lane >> 4;     // k-quarter (A), row-quarter (C)

    for (int t = gbid * 4 + wv; t < N_TILES; t += nblk * 4) {
        const int row0 = t * 16;
        const float* xrow = &x[(size_t)(row0 + r16) * IN_CH + q * 8];
        f32x4 acc[4] = {{0.f,0.f,0.f,0.f},{0.f,0.f,0.f,0.f},
                        {0.f,0.f,0.f,0.f},{0.f,0.f,0.f,0.f}};
        #pragma unroll
        for (int kt = 0; kt < 8; ++kt) {
            float4 x0 = *(const float4*)&xrow[kt * 32];
            float4 x1 = *(const float4*)&xrow[kt * 32 + 4];
            unsigned p0, p1, p2, p3;
            asm("v_cvt_pk_bf16_f32 %0, %1, %2" : "=v"(p0) : "v"(x0.x), "v"(x0.y));
            asm("v_cvt_pk_bf16_f32 %0, %1, %2" : "=v"(p1) : "v"(x0.z), "v"(x0.w));
            asm("v_cvt_pk_bf16_f32 %0, %1, %2" : "=v"(p2) : "v"(x1.x), "v"(x1.y));
            asm("v_cvt_pk_bf16_f32 %0, %1, %2" : "=v"(p3) : "v"(x1.z), "v"(x1.w));
            u32x4 au = {p0, p1, p2, p3};
            bshort8 af = __builtin_bit_cast(bshort8, au);
            #pragma unroll
            for (int ct = 0; ct < 4; ++ct) {
                bshort8 bf = *(const bshort8*)&Wf[kt][ct][lane][0];
                acc[ct] = __builtin_amdgcn_mfma_f32_16x16x32_bf16(af, bf, acc[ct], 0, 0, 0);
            }
        }
        #pragma unroll
        for (int ct = 0; ct < 4; ++ct) {
            #pragma unroll
            for (int r = 0; r < 4; ++r) {
                int row = row0 + q * 4 + r;
                hs[(size_t)row * OUT_CH + ct * 16 + r16] = f2bf(acc[ct][r]);
            }
        }
    }
}

// ---------------------------------------------------------------------------
// Standalone partition, now 782 blocks (T_PART=4096) => ~3 blocks/CU, 2048
// threads/CU: latency of scattered writes + LDS atomics hidden by TLP.
// Pass 1 histograms + register-caches dst (4 vec-iters); pass 2 reads only src.
__global__ __launch_bounds__(512) void partition_kernel(const int* __restrict__ ei32,
                                                        const long long* __restrict__ ei64,
                                                        const int* __restrict__ flag,
                                                        unsigned* __restrict__ gcnt,
                                                        unsigned* __restrict__ edg) {
    __shared__ unsigned hist[K_BKT];
    __shared__ unsigned cur[K_BKT];
    const bool is64 = (*flag != 0);
    const int tid = threadIdx.x;
    const int start = blockIdx.x * T_PART;
    const int end   = min(start + T_PART, N_EDGES);
    const int pbase = start >> 1;
    const int pend  = end >> 1;
    unsigned dcx[4], dcy[4];

    for (int k = tid; k < K_BKT; k += 512) hist[k] = 0u;
    __syncthreads();
    if (is64) {
        const longlong2* d2 = (const longlong2*)&ei64[N_EDGES];
        #pragma unroll
        for (int it = 0; it < 4; ++it) {
            int i = pbase + it * 512 + tid;
            if (i < pend) {
                longlong2 d = d2[i];
                dcx[it] = (unsigned)(int)d.x;
                dcy[it] = (unsigned)(int)d.y;
                atomicAdd(&hist[dcx[it] >> BKT_SHIFT], 1u);
                atomicAdd(&hist[dcy[it] >> BKT_SHIFT], 1u);
            }
        }
    } else {
        const int2* d2 = (const int2*)&ei32[N_EDGES];
        #pragma unroll
        for (int it = 0; it < 4; ++it) {
            int i = pbase + it * 512 + tid;
            if (i < pend) {
                int2 d = d2[i];
                dcx[it] = (unsigned)d.x;
                dcy[it] = (unsigned)d.y;
                atomicAdd(&hist[dcx[it] >> BKT_SHIFT], 1u);
                atomicAdd(&hist[dcy[it] >> BKT_SHIFT], 1u);
            }
        }
    }
    __syncthreads();
    for (int k = tid; k < K_BKT; k += 512) {
        unsigned c = hist[k];
        unsigned base = c ? atomicAdd(&gcnt[k], c) : 0u;
        cur[k] = base + (unsigned)k * BKT_CAP;
    }
    __syncthreads();
    if (is64) {
        const longlong2* s2 = (const longlong2*)&ei64[0];
        #pragma unroll
        for (int it = 0; it < 4; ++it) {
            int i = pbase + it * 512 + tid;
            if (i < pend) {
                longlong2 s = s2[i];
                unsigned dx = dcx[it], dy = dcy[it];
                unsigned p0 = atomicAdd(&cur[dx >> BKT_SHIFT], 1u);
                edg[p0] = (unsigned)s.x | ((dx & (BKT_R - 1)) << 17);
                unsigned p1 = atomicAdd(&cur[dy >> BKT_SHIFT], 1u);
                edg[p1] = (unsigned)s.y | ((dy & (BKT_R - 1)) << 17);
            }
        }
    } else {
        const int2* s2 = (const int2*)&ei32[0];
        #pragma unroll
        for (int it = 0; it < 4; ++it) {
            int i = pbase + it * 512 + tid;
            if (i < pend) {
                int2 s = s2[i];
                unsigned dx = dcx[it], dy = dcy[it];
                unsigned p0 = atomicAdd(&cur[dx >> BKT_SHIFT], 1u);
                edg[p0] = (unsigned)s.x | ((dx & (BKT_R - 1)) << 17);
                unsigned p1 = atomicAdd(&cur[dy >> BKT_SHIFT], 1u);
                edg[p1] = (unsigned)s.y | ((dy & (BKT_R - 1)) << 17);
            }
        }
    }
}

// ---------------------------------------------------------------------------
// FUSED sort2 + gemm (round-11..13-proven): blocks [0, K_BKT) counting-sort
// their bucket (LDS-staged, in place -> nse/dinv); blocks [K_BKT, +NBLK_GEMM)
// gemm.
__global__ __launch_bounds__(256) void sortgemm_kernel(unsigned* __restrict__ edg,
                                                       const unsigned* __restrict__ gcnt,
                                                       uint2* __restrict__ nse,
                                                       float* __restrict__ dinv,
                                                       const float* __restrict__ x,
                                                       const float* __restrict__ W,
                                                       unsigned short* __restrict__ hs) {
    __shared__ char smem[32768];
    const int bid = blockIdx.x;
    if (bid < K_BKT) {
        unsigned* ld   = (unsigned*)smem;            // 24576 B
        unsigned* hist = (unsigned*)(smem + 24576);  // 512 B
        unsigned* cur  = (unsigned*)(smem + 25088);  // 512 B
        const int k = bid;
        const int t = threadIdx.x;
        const unsigned cnt = min(gcnt[k], (unsigned)BKT_CAP);
        const unsigned base = (unsigned)k * BKT_CAP;

        for (unsigned j = t; j < cnt; j += 256) ld[j] = edg[base + j];
        if (t < BKT_R) hist[t] = 0u;
        __syncthreads();
        for (unsigned j = t; j < cnt; j += 256)
            atomicAdd(&hist[ld[j] >> 17], 1u);
        __syncthreads();
        if (t < BKT_R) cur[t] = hist[t];
        __syncthreads();
        #pragma unroll
        for (int d = 1; d < BKT_R; d <<= 1) {
            unsigned v = (t < BKT_R && t >= d) ? cur[t - d] : 0u;
            __syncthreads();
            if (t < BKT_R) cur[t] += v;
            __syncthreads();
        }
        if (t < BKT_R) {
            unsigned mydeg = hist[t];
            unsigned start = base + cur[t] - mydeg;   // exclusive, padded coords
            int n = k * BKT_R + t;
            if (n < N_NODES) {
                nse[n] = make_uint2(start, start + mydeg);
                dinv[n] = rsqrtf((float)(mydeg + 1u));
            }
            cur[t] = start;
        }
        __syncthreads();
        for (unsigned j = t; j < cnt; j += 256) {
            unsigned p = ld[j];
            unsigned pos = atomicAdd(&cur[p >> 17], 1u);
            edg[pos] = p & 0x1FFFF;     // sorted src id
        }
    } else {
        gemm_body(smem, bid - K_BKT, NBLK_GEMM, x, W, hs);
    }
}

// gemm-only wrapper (fallback path)
__global__ __launch_bounds__(256) void gemm_only_kernel(const float* __restrict__ x,
                                                        const float* __restrict__ W,
                                                        unsigned short* __restrict__ hs) {
    __shared__ char smem[32768];
    gemm_body(smem, blockIdx.x, gridDim.x, x, W, hs);
}

// ---------------------------------------------------------------------------
// Wave per node, quarter-wave per edge, 32/16/4/1 edge loops (round-13 code;
// reduce is at its measured structural floor ~78us).
__global__ __launch_bounds__(256) void reduce_kernel(const unsigned short* __restrict__ hs,
                                                     const float* __restrict__ dinv,
                                                     const uint2* __restrict__ nse,
                                                     const int* __restrict__ ssrc,
                                                     const float* __restrict__ b,
                                                     float* __restrict__ out) {
    const int n = blockIdx.x * 4 + (threadIdx.x >> 6);
    const int lane = threadIdx.x & 63;
    const int q = lane >> 4;
    const int l16 = lane & 15;
    if (n >= N_NODES) return;
    const uint2* h8 = (const uint2*)hs;   // one row = 16 uint2
    const float dn = dinv[n];
    f32x2 A01 = {0.f, 0.f}, A23 = {0.f, 0.f};
    {   // self-loop: h[n]*dinv[n]; counted once (q==0)
        uint2 sv = h8[(size_t)n * 16 + l16];
        if (q == 0) {
            f32x2 dnv = {dn, dn};
            A01 = up2(sv.x) * dnv;
            A23 = up2(sv.y) * dnv;
        }
    }
    uint2 se = nse[n];
    unsigned j = se.x;
    const unsigned end = se.y;
    for (; j + 32 <= end; j += 32) {
        int s0 = ssrc[j + q];
        int s1 = ssrc[j + 4 + q];
        int s2 = ssrc[j + 8 + q];
        int s3 = ssrc[j + 12 + q];
        int s4 = ssrc[j + 16 + q];
        int s5 = ssrc[j + 20 + q];
        int s6 = ssrc[j + 24 + q];
        int s7 = ssrc[j + 28 + q];
        float f0 = dinv[s0], f1 = dinv[s1], f2 = dinv[s2], f3 = dinv[s3];
        float f4 = dinv[s4], f5 = dinv[s5], f6 = dinv[s6], f7 = dinv[s7];
        uint2 v0 = h8[(size_t)s0 * 16 + l16];
        uint2 v1 = h8[(size_t)s1 * 16 + l16];
        uint2 v2 = h8[(size_t)s2 * 16 + l16];
        uint2 v3 = h8[(size_t)s3 * 16 + l16];
        uint2 v4 = h8[(size_t)s4 * 16 + l16];
        uint2 v5 = h8[(size_t)s5 * 16 + l16];
        uint2 v6 = h8[(size_t)s6 * 16 + l16];
        uint2 v7 = h8[(size_t)s7 * 16 + l16];
        f32x2 F0 = {f0, f0}, F1 = {f1, f1}, F2 = {f2, f2}, F3 = {f3, f3};
        f32x2 F4 = {f4, f4}, F5 = {f5, f5}, F6 = {f6, f6}, F7 = {f7, f7};
        A01 += up2(v0.x) * F0; A23 += up2(v0.y) * F0;
        A01 += up2(v1.x) * F1; A23 += up2(v1.y) * F1;
        A01 += up2(v2.x) * F2; A23 += up2(v2.y) * F2;
        A01 += up2(v3.x) * F3; A23 += up2(v3.y) * F3;
        A01 += up2(v4.x) * F4; A23 += up2(v4.y) * F4;
        A01 += up2(v5.x) * F5; A23 += up2(v5.y) * F5;
        A01 += up2(v6.x) * F6; A23 += up2(v6.y) * F6;
        A01 += up2(v7.x) * F7; A23 += up2(v7.y) * F7;
    }
    for (; j + 16 <= end; j += 16) {
        int s0 = ssrc[j + q];
        int s1 = ssrc[j + 4 + q];
        int s2 = ssrc[j + 8 + q];
        int s3 = ssrc[j + 12 + q];
        float f0 = dinv[s0], f1 = dinv[s1], f2 = dinv[s2], f3 = dinv[s3];
        uint2 v0 = h8[(size_t)s0 * 16 + l16];
        uint2 v1 = h8[(size_t)s1 * 16 + l16];
        uint2 v2 = h8[(size_t)s2 * 16 + l16];
        uint2 v3 = h8[(size_t)s3 * 16 + l16];
        f32x2 F0 = {f0, f0}, F1 = {f1, f1}, F2 = {f2, f2}, F3 = {f3, f3};
        A01 += up2(v0.x) * F0; A23 += up2(v0.y) * F0;
        A01 += up2(v1.x) * F1; A23 += up2(v1.y) * F1;
        A01 += up2(v2.x) * F2; A23 += up2(v2.y) * F2;
        A01 += up2(v3.x) * F3; A23 += up2(v3.y) * F3;
    }
    for (; j + 4 <= end; j += 4) {
        int s = ssrc[j + q];
        float f = dinv[s];
        uint2 v = h8[(size_t)s * 16 + l16];
        f32x2 F = {f, f};
        A01 += up2(v.x) * F; A23 += up2(v.y) * F;
    }
    unsigned rem = end - j;
    if ((unsigned)q < rem) {
        int s = ssrc[j + q];
        float f = dinv[s];
        uint2 v = h8[(size_t)s * 16 + l16];
        f32x2 F = {f, f};
        A01 += up2(v.x) * F; A23 += up2(v.y) * F;
    }
    float a0 = A01.x, a1 = A01.y, a2 = A23.x, a3 = A23.y;
    a0 += __shfl_xor(a0, 16); a0 += __shfl_xor(a0, 32);
    a1 += __shfl_xor(a1, 16); a1 += __shfl_xor(a1, 32);
    a2 += __shfl_xor(a2, 16); a2 += __shfl_xor(a2, 32);
    a3 += __shfl_xor(a3, 16); a3 += __shfl_xor(a3, 32);
    float4 bb = ((const float4*)b)[l16];
    float v0 = fmaxf(fmaf(a0, dn, bb.x), 0.f);
    float v1 = fmaxf(fmaf(a1, dn, bb.y), 0.f);
    float v2 = fmaxf(fmaf(a2, dn, bb.z), 0.f);
    float v3 = fmaxf(fmaf(a3, dn, bb.w), 0.f);
    float m = fmaxf(fmaxf(v0, v1), fmaxf(v2, v3));
    #pragma unroll
    for (int o = 8; o; o >>= 1) m = fmaxf(m, __shfl_xor(m, o));
    float sum = expf(v0 - m) + expf(v1 - m) + expf(v2 - m) + expf(v3 - m);
    #pragma unroll
    for (int o = 8; o; o >>= 1) sum += __shfl_xor(sum, o);
    float ls = logf(sum);
    if (q == 0) {
        float4 r;
        r.x = (v0 - m) - ls; r.y = (v1 - m) - ls;
        r.z = (v2 - m) - ls; r.w = (v3 - m) - ls;
        *(float4*)&out[(size_t)n * OUT_CH + l16 * 4] = r;
    }
}

// ---------------------------------------------------------------------------
// Fallback (atomic scatter) path, only if ws is too small for the CSR path.
__global__ __launch_bounds__(256) void deg_kernel(const int* __restrict__ ei32,
                                                  const long long* __restrict__ ei64,
                                                  const int* __restrict__ flag,
                                                  unsigned* __restrict__ deg) {
    const bool is64 = (*flag != 0);
    int i = blockIdx.x * blockDim.x + threadIdx.x;
    const int stride = gridDim.x * blockDim.x;
    for (; i < N_EDGES; i += stride) {
        int d = load_idx(ei32, ei64, is64, (long long)N_EDGES + i);
        atomicAdd(&deg[d], 1u);
    }
}

__global__ __launch_bounds__(256) void dinv_kernel(const unsigned* __restrict__ deg,
                                                   float* __restrict__ dinv) {
    int i = blockIdx.x * blockDim.x + threadIdx.x;
    if (i < N_NODES) dinv[i] = rsqrtf((float)(deg[i] + 1u));
}

__global__ __launch_bounds__(256) void scatter_kernel(const int* __restrict__ ei32,
                                                      const long long* __restrict__ ei64,
                                                      const int* __restrict__ flag,
                                                      const unsigned short* __restrict__ hs,
                                                      const float* __restrict__ dinv,
                                                      float* __restrict__ out) {
    const bool is64 = (*flag != 0);
    const int lane = threadIdx.x & 63;
    int w = blockIdx.x * (blockDim.x >> 6) + (threadIdx.x >> 6);
    const int nw = gridDim.x * (blockDim.x >> 6);
    for (int e = w; e < N_EDGES; e += nw) {
        int s = load_idx(ei32, ei64, is64, e);
        int d = load_idx(ei32, ei64, is64, (long long)N_EDGES + e);
        unsigned short us = hs[(size_t)s * OUT_CH + lane];
        float hv = __builtin_bit_cast(float, (unsigned)us << 16);
        atomicAdd(&out[(size_t)d * OUT_CH + lane], hv * dinv[s] * dinv[d]);
    }
}

__global__ __launch_bounds__(256) void final_kernel(const unsigned short* __restrict__ hs,
                                                    const float* __restrict__ dinv,
                                                    const float* __restrict__ b,
                                                    float* __restrict__ out) {
    const int lane = threadIdx.x & 63;
    int w = blockIdx.x * (blockDim.x >> 6) + (threadIdx.x >> 6);
    const int nw = gridDim.x * (blockDim.x >> 6);
    const float bias = b[lane];
    for (int n = w; n < N_NODES; n += nw) {
        float di = dinv[n];
        unsigned short us = hs[(size_t)n * OUT_CH + lane];
        float hv = __builtin_bit_cast(float, (unsigned)us << 16);
        float v = out[(size_t)n * OUT_CH + lane] + hv * di * di + bias;
        v = fmaxf(v, 0.f);
        float m = v;
        #pragma unroll
        for (int o = 32; o; o >>= 1) m = fmaxf(m, __shfl_xor(m, o));
        float ex = expf(v - m);
        float sum = ex;
        #pragma unroll
        for (int o = 32; o; o >>= 1) sum += __shfl_xor(sum, o);
        out[(size_t)n * OUT_CH + lane] = (v - m) - logf(sum);
    }
}

// ---------------------------------------------------------------------------
extern "C" void kernel_launch(void* const* d_in, const int* in_sizes, int n_in,
                              void* d_out, int out_size, void* d_ws, size_t ws_size,
                              hipStream_t stream) {
    const float* x  = (const float*)d_in[0];
    const void*  ei = d_in[1];
    const float* W  = (const float*)d_in[2];
    const float* b  = (const float*)d_in[3];
    float* out = (float*)d_out;

    char* ws = (char*)d_ws;
    int* flag = (int*)(ws + WS_FLAG_OFF);
    unsigned* gcnt = (unsigned*)(ws + WS_GCNT_OFF);

    const int* ei32       = (const int*)ei;
    const long long* ei64 = (const long long*)ei;

    probe_kernel<<<1, 64, 0, stream>>>((const unsigned*)ei, flag, gcnt);

    if (ws_size >= (size_t)WS_NEED) {
        float*    dinv = (float*)(ws + WS_DINV_OFF);
        uint2*    nse  = (uint2*)(ws + WS_NSE_OFF);
        unsigned* edg  = (unsigned*)(ws + WS_EDG_OFF);
        unsigned short* hs = (unsigned short*)(ws + WS_H_OFF);

        partition_kernel<<<NBLK_PART, 512, 0, stream>>>(ei32, ei64, flag, gcnt, edg);
        sortgemm_kernel<<<K_BKT + NBLK_GEMM, 256, 0, stream>>>(
            edg, gcnt, nse, dinv, x, W, hs);
        reduce_kernel<<<(N_NODES + 3) / 4, 256, 0, stream>>>(
            hs, dinv, nse, (const int*)edg, b, out);
    } else {
        unsigned* deg  = (unsigned*)(ws + WSF_DEG_OFF);
        float*    dinv = (float*)(ws + WSF_DINV_OFF);
        unsigned short* hs = (unsigned short*)(ws + WSF_H_OFF);
        hipMemsetAsync(deg, 0, (size_t)N_NODES * sizeof(unsigned), stream);
        hipMemsetAsync(d_out, 0, (size_t)out_size * sizeof(float), stream);
        deg_kernel<<<2048, 256, 0, stream>>>(ei32, ei64, flag, deg);
        dinv_kernel<<<(N_NODES + 255) / 256, 256, 0, stream>>>(deg, dinv);
        gemm_only_kernel<<<NBLK_GEMM, 256, 0, stream>>>(x, W, hs);
        scatter_kernel<<<2048, 256, 0, stream>>>(ei32, ei64, flag, hs, dinv, out);
        final_kernel<<<1024, 256, 0, stream>>>(hs, dinv, b, out);
    }
}

// Round 15
// 157.838 us; speedup vs baseline: 1.0931x; 1.0931x over previous
//
#include <hip/hip_runtime.h>
#include <cstddef>
#include <cstdint>

#define N_NODES 100000
#define IN_CH 256
#define OUT_CH 64
#define N_EDGES 3200000

// bucketing: 128 nodes per bucket, fixed-capacity slots
#define BKT_SHIFT 7
#define BKT_R     128
#define K_BKT     782                 // ceil(100000/128)
#define BKT_CAP   6144                // mean 4096 + 32 sigma; slots of 24KB
#define T_PART    8192                // edges per partition block
#define NBLK_PART ((N_EDGES + T_PART - 1) / T_PART)   // 391
#define NBLK_GEMM 512
#define N_TILES   (N_NODES / 16)      // 6250

// ---- ws layout (bytes) ----
#define WS_FLAG_OFF   0
#define WS_GCNT_OFF   64              // 782 u32 bucket fill counts
#define WS_DINV_OFF   4096            // 400000 B
#define WS_NSE_OFF    404096          // 100000 uint2 = 800000 B
#define WS_EDG_OFF    1204224         // 782*6144*4 = 19,218,432 B (pairs -> sorted src)
#define WS_H_OFF      20422656        // bf16 h: 100000*64*2 = 12.8MB (unscaled)
#define WS_NEED       33222656

// ---- fallback (atomic) layout ----
#define WSF_DEG_OFF   4096
#define WSF_DINV_OFF  404096
#define WSF_H_OFF     804096

typedef __attribute__((ext_vector_type(8))) short bshort8;
typedef __attribute__((ext_vector_type(4))) float f32x4;
typedef __attribute__((ext_vector_type(2))) float f32x2;
typedef __attribute__((ext_vector_type(4))) unsigned u32x4;

// ---------------------------------------------------------------------------
static __device__ __forceinline__ unsigned short f2bf(float f) {
    unsigned u = __builtin_bit_cast(unsigned, f);
    u += 0x7FFFu + ((u >> 16) & 1u);     // RNE (finite inputs)
    return (unsigned short)(u >> 16);
}
static __device__ __forceinline__ float bflo(unsigned u) {
    return __builtin_bit_cast(float, u << 16);
}
static __device__ __forceinline__ float bfhi(unsigned u) {
    return __builtin_bit_cast(float, u & 0xFFFF0000u);
}
static __device__ __forceinline__ f32x2 up2(unsigned u) {
    f32x2 r;
    r.x = __builtin_bit_cast(float, u << 16);
    r.y = __builtin_bit_cast(float, u & 0xFFFF0000u);
    return r;
}

// ---------------------------------------------------------------------------
// probe: detect int64 vs int32 edge layout AND zero the gcnt counters.
__global__ void probe_kernel(const unsigned* __restrict__ ei, int* __restrict__ flag,
                             unsigned* __restrict__ gcnt) {
    if (blockIdx.x == 0) {
        for (int k = threadIdx.x; k < K_BKT; k += 64) gcnt[k] = 0u;
        if (threadIdx.x == 0) {
            int all0 = 1;
            for (int i = 0; i < 16; ++i) all0 &= (ei[2 * i + 1] == 0u);
            *flag = all0;  // 1 => int64 layout, 0 => int32 layout
        }
    }
}

__device__ __forceinline__ int load_idx(const int* ei32, const long long* ei64,
                                        bool is64, long long pos) {
    return is64 ? (int)ei64[pos] : ei32[pos];
}

// ---------------------------------------------------------------------------
// Shared gemm body (256 threads, 4 waves): h = x @ W, bf16 store, UNSCALED.
// (round-9..13-proven code, unchanged)
static __device__ __forceinline__ void gemm_body(char* smem, int gbid, int nblk,
                                                 const float* __restrict__ x,
                                                 const float* __restrict__ W,
                                                 unsigned short* __restrict__ hs) {
    unsigned short (*Wf)[4][64][8] = (unsigned short (*)[4][64][8])smem;
    const int tid = threadIdx.x;
    const int lane = tid & 63;
    const int wv = tid >> 6;           // 4 waves

    for (int i = tid; i < 8 * 4 * 64 * 8; i += 256) {
        int kt = i >> 11;
        int rem = i & 2047;
        int ct = rem >> 9;
        int rem2 = rem & 511;
        int l = rem2 >> 3;
        int j = rem2 & 7;
        int kk = kt * 32 + (l >> 4) * 8 + j;
        int cc = ct * 16 + (l & 15);
        ((unsigned short*)Wf)[i] = f2bf(W[(size_t)kk * OUT_CH + cc]);
    }
    __syncthreads();

    const int r16 = lane & 15;   // A row within tile
    const int q = lane >> 4;     // k-quarter (A), row-quarter (C)

    for (int t = gbid * 4 + wv; t < N_TILES; t += nblk * 4) {
        const int row0 = t * 16;
        const float* xrow = &x[(size_t)(row0 + r16) * IN_CH + q * 8];
        f32x4 acc[4] = {{0.f,0.f,0.f,0.f},{0.f,0.f,0.f,0.f},
                        {0.f,0.f,0.f,0.f},{0.f,0.f,0.f,0.f}};
        #pragma unroll
        for (int kt = 0; kt < 8; ++kt) {
            float4 x0 = *(const float4*)&xrow[kt * 32];
            float4 x1 = *(const float4*)&xrow[kt * 32 + 4];
            unsigned p0, p1, p2, p3;
            asm("v_cvt_pk_bf16_f32 %0, %1, %2" : "=v"(p0) : "v"(x0.x), "v"(x0.y));
            asm("v_cvt_pk_bf16_f32 %0, %1, %2" : "=v"(p1) : "v"(x0.z), "v"(x0.w));
            asm("v_cvt_pk_bf16_f32 %0, %1, %2" : "=v"(p2) : "v"(x1.x), "v"(x1.y));
            asm("v_cvt_pk_bf16_f32 %0, %1, %2" : "=v"(p3) : "v"(x1.z), "v"(x1.w));
            u32x4 au = {p0, p1, p2, p3};
            bshort8 af = __builtin_bit_cast(bshort8, au);
            #pragma unroll
            for (int ct = 0; ct < 4; ++ct) {
                bshort8 bf = *(const bshort8*)&Wf[kt][ct][lane][0];
                acc[ct] = __builtin_amdgcn_mfma_f32_16x16x32_bf16(af, bf, acc[ct], 0, 0, 0);
            }
        }
        #pragma unroll
        for (int ct = 0; ct < 4; ++ct) {
            #pragma unroll
            for (int r = 0; r < 4; ++r) {
                int row = row0 + q * 4 + r;
                hs[(size_t)row * OUT_CH + ct * 16 + r16] = f2bf(acc[ct][r]);
            }
        }
    }
}

// ---------------------------------------------------------------------------
// Partition with block-level LDS counting sort: pairs leave the block in
// bucket-sorted order, so consecutive LANES write consecutive global
// addresses within each per-(block,bucket) run => wave-coalesced stores.
// Phases: hist(+dst reg-cache) -> wave0 shfl-scan -> gcnt reservation
// (hist[] rewritten in place to global run base) -> LDS rank-scatter ->
// thread-linear drain with per-j binary search.
__global__ __launch_bounds__(512) void partition_kernel(const int* __restrict__ ei32,
                                                        const long long* __restrict__ ei64,
                                                        const int* __restrict__ flag,
                                                        unsigned* __restrict__ gcnt,
                                                        unsigned* __restrict__ edg) {
    __shared__ unsigned ordered[T_PART];   // 32 KB
    __shared__ unsigned hist[K_BKT];       // counts -> then global run base
    __shared__ unsigned scan[K_BKT + 1];   // block-local exclusive scan
    __shared__ unsigned cur[K_BKT];        // running rank cursor
    const bool is64 = (*flag != 0);
    const int tid = threadIdx.x;
    const int lane = tid & 63;
    const int start = blockIdx.x * T_PART;
    const int end   = min(start + T_PART, N_EDGES);
    const int total = end - start;
    const int pbase = start >> 1;
    const int pend  = end >> 1;
    unsigned dcx[8], dcy[8];

    for (int k = tid; k < K_BKT; k += 512) hist[k] = 0u;
    __syncthreads();
    // pass 1: histogram + register-cache dst ids
    if (is64) {
        const longlong2* d2 = (const longlong2*)&ei64[N_EDGES];
        #pragma unroll
        for (int it = 0; it < 8; ++it) {
            int i = pbase + it * 512 + tid;
            if (i < pend) {
                longlong2 d = d2[i];
                dcx[it] = (unsigned)(int)d.x;
                dcy[it] = (unsigned)(int)d.y;
                atomicAdd(&hist[dcx[it] >> BKT_SHIFT], 1u);
                atomicAdd(&hist[dcy[it] >> BKT_SHIFT], 1u);
            }
        }
    } else {
        const int2* d2 = (const int2*)&ei32[N_EDGES];
        #pragma unroll
        for (int it = 0; it < 8; ++it) {
            int i = pbase + it * 512 + tid;
            if (i < pend) {
                int2 d = d2[i];
                dcx[it] = (unsigned)d.x;
                dcy[it] = (unsigned)d.y;
                atomicAdd(&hist[dcx[it] >> BKT_SHIFT], 1u);
                atomicAdd(&hist[dcy[it] >> BKT_SHIFT], 1u);
            }
        }
    }
    __syncthreads();
    // wave-0 chunked shfl scan of hist -> scan[1..K_BKT], scan[0]=0
    if (tid < 64) {
        if (tid == 0) scan[0] = 0u;
        unsigned run = 0u;
        for (int c0 = 0; c0 < K_BKT; c0 += 64) {
            int k = c0 + lane;
            unsigned v = (k < K_BKT) ? hist[k] : 0u;
            unsigned incl = v;
            #pragma unroll
            for (int d = 1; d < 64; d <<= 1) {
                unsigned tq = __shfl_up(incl, d);
                if (lane >= d) incl += tq;
            }
            if (k < K_BKT) scan[k + 1] = run + incl;
            run += __shfl(incl, 63);
        }
    }
    __syncthreads();
    // reservation: hist[k] <- global run base (in place); cur[k] <- scan[k]
    for (int k = tid; k < K_BKT; k += 512) {
        unsigned c = hist[k];
        unsigned base = c ? atomicAdd(&gcnt[k], c) : 0u;
        hist[k] = base + (unsigned)k * BKT_CAP;
        cur[k] = scan[k];
    }
    __syncthreads();
    // pass 2: read src stream, rank-scatter pairs into LDS ordered[]
    if (is64) {
        const longlong2* s2 = (const longlong2*)&ei64[0];
        #pragma unroll
        for (int it = 0; it < 8; ++it) {
            int i = pbase + it * 512 + tid;
            if (i < pend) {
                longlong2 s = s2[i];
                unsigned dx = dcx[it], dy = dcy[it];
                unsigned p0 = atomicAdd(&cur[dx >> BKT_SHIFT], 1u);
                ordered[p0] = (unsigned)s.x | ((dx & (BKT_R - 1)) << 17);
                unsigned p1 = atomicAdd(&cur[dy >> BKT_SHIFT], 1u);
                ordered[p1] = (unsigned)s.y | ((dy & (BKT_R - 1)) << 17);
            }
        }
    } else {
        const int2* s2 = (const int2*)&ei32[0];
        #pragma unroll
        for (int it = 0; it < 8; ++it) {
            int i = pbase + it * 512 + tid;
            if (i < pend) {
                int2 s = s2[i];
                unsigned dx = dcx[it], dy = dcy[it];
                unsigned p0 = atomicAdd(&cur[dx >> BKT_SHIFT], 1u);
                ordered[p0] = (unsigned)s.x | ((dx & (BKT_R - 1)) << 17);
                unsigned p1 = atomicAdd(&cur[dy >> BKT_SHIFT], 1u);
                ordered[p1] = (unsigned)s.y | ((dy & (BKT_R - 1)) << 17);
            }
        }
    }
    __syncthreads();
    // pass 3: drain in sorted order; adjacent lanes -> adjacent global addrs.
    for (int j = tid; j < total; j += 512) {
        unsigned pr = ordered[j];
        int lo = 0, hi = K_BKT - 1;   // find max k with scan[k] <= j
        while (lo < hi) {
            int mid = (lo + hi + 1) >> 1;
            if (scan[mid] <= (unsigned)j) lo = mid; else hi = mid - 1;
        }
        edg[hist[lo] + ((unsigned)j - scan[lo])] = pr;
    }
}

// ---------------------------------------------------------------------------
// FUSED sort2 + gemm (round-11..13-proven): blocks [0, K_BKT) counting-sort
// their bucket (LDS-staged, in place -> nse/dinv); blocks [K_BKT, +NBLK_GEMM)
// gemm.
__global__ __launch_bounds__(256) void sortgemm_kernel(unsigned* __restrict__ edg,
                                                       const unsigned* __restrict__ gcnt,
                                                       uint2* __restrict__ nse,
                                                       float* __restrict__ dinv,
                                                       const float* __restrict__ x,
                                                       const float* __restrict__ W,
                                                       unsigned short* __restrict__ hs) {
    __shared__ char smem[32768];
    const int bid = blockIdx.x;
    if (bid < K_BKT) {
        unsigned* ld   = (unsigned*)smem;            // 24576 B
        unsigned* hist = (unsigned*)(smem + 24576);  // 512 B
        unsigned* cur  = (unsigned*)(smem + 25088);  // 512 B
        const int k = bid;
        const int t = threadIdx.x;
        const unsigned cnt = min(gcnt[k], (unsigned)BKT_CAP);
        const unsigned base = (unsigned)k * BKT_CAP;

        for (unsigned j = t; j < cnt; j += 256) ld[j] = edg[base + j];
        if (t < BKT_R) hist[t] = 0u;
        __syncthreads();
        for (unsigned j = t; j < cnt; j += 256)
            atomicAdd(&hist[ld[j] >> 17], 1u);
        __syncthreads();
        if (t < BKT_R) cur[t] = hist[t];
        __syncthreads();
        #pragma unroll
        for (int d = 1; d < BKT_R; d <<= 1) {
            unsigned v = (t < BKT_R && t >= d) ? cur[t - d] : 0u;
            __syncthreads();
            if (t < BKT_R) cur[t] += v;
            __syncthreads();
        }
        if (t < BKT_R) {
            unsigned mydeg = hist[t];
            unsigned start = base + cur[t] - mydeg;   // exclusive, padded coords
            int n = k * BKT_R + t;
            if (n < N_NODES) {
                nse[n] = make_uint2(start, start + mydeg);
                dinv[n] = rsqrtf((float)(mydeg + 1u));
            }
            cur[t] = start;
        }
        __syncthreads();
        for (unsigned j = t; j < cnt; j += 256) {
            unsigned p = ld[j];
            unsigned pos = atomicAdd(&cur[p >> 17], 1u);
            edg[pos] = p & 0x1FFFF;     // sorted src id
        }
    } else {
        gemm_body(smem, bid - K_BKT, NBLK_GEMM, x, W, hs);
    }
}

// gemm-only wrapper (fallback path)
__global__ __launch_bounds__(256) void gemm_only_kernel(const float* __restrict__ x,
                                                        const float* __restrict__ W,
                                                        unsigned short* __restrict__ hs) {
    __shared__ char smem[32768];
    gemm_body(smem, blockIdx.x, gridDim.x, x, W, hs);
}

// ---------------------------------------------------------------------------
// Wave per node, quarter-wave per edge, 32/16/4/1 edge loops (round-13 code;
// reduce is at its measured structural floor ~78us).
__global__ __launch_bounds__(256) void reduce_kernel(const unsigned short* __restrict__ hs,
                                                     const float* __restrict__ dinv,
                                                     const uint2* __restrict__ nse,
                                                     const int* __restrict__ ssrc,
                                                     const float* __restrict__ b,
                                                     float* __restrict__ out) {
    const int n = blockIdx.x * 4 + (threadIdx.x >> 6);
    const int lane = threadIdx.x & 63;
    const int q = lane >> 4;
    const int l16 = lane & 15;
    if (n >= N_NODES) return;
    const uint2* h8 = (const uint2*)hs;   // one row = 16 uint2
    const float dn = dinv[n];
    f32x2 A01 = {0.f, 0.f}, A23 = {0.f, 0.f};
    {   // self-loop: h[n]*dinv[n]; counted once (q==0)
        uint2 sv = h8[(size_t)n * 16 + l16];
        if (q == 0) {
            f32x2 dnv = {dn, dn};
            A01 = up2(sv.x) * dnv;
            A23 = up2(sv.y) * dnv;
        }
    }
    uint2 se = nse[n];
    unsigned j = se.x;
    const unsigned end = se.y;
    for (; j + 32 <= end; j += 32) {
        int s0 = ssrc[j + q];
        int s1 = ssrc[j + 4 + q];
        int s2 = ssrc[j + 8 + q];
        int s3 = ssrc[j + 12 + q];
        int s4 = ssrc[j + 16 + q];
        int s5 = ssrc[j + 20 + q];
        int s6 = ssrc[j + 24 + q];
        int s7 = ssrc[j + 28 + q];
        float f0 = dinv[s0], f1 = dinv[s1], f2 = dinv[s2], f3 = dinv[s3];
        float f4 = dinv[s4], f5 = dinv[s5], f6 = dinv[s6], f7 = dinv[s7];
        uint2 v0 = h8[(size_t)s0 * 16 + l16];
        uint2 v1 = h8[(size_t)s1 * 16 + l16];
        uint2 v2 = h8[(size_t)s2 * 16 + l16];
        uint2 v3 = h8[(size_t)s3 * 16 + l16];
        uint2 v4 = h8[(size_t)s4 * 16 + l16];
        uint2 v5 = h8[(size_t)s5 * 16 + l16];
        uint2 v6 = h8[(size_t)s6 * 16 + l16];
        uint2 v7 = h8[(size_t)s7 * 16 + l16];
        f32x2 F0 = {f0, f0}, F1 = {f1, f1}, F2 = {f2, f2}, F3 = {f3, f3};
        f32x2 F4 = {f4, f4}, F5 = {f5, f5}, F6 = {f6, f6}, F7 = {f7, f7};
        A01 += up2(v0.x) * F0; A23 += up2(v0.y) * F0;
        A01 += up2(v1.x) * F1; A23 += up2(v1.y) * F1;
        A01 += up2(v2.x) * F2; A23 += up2(v2.y) * F2;
        A01 += up2(v3.x) * F3; A23 += up2(v3.y) * F3;
        A01 += up2(v4.x) * F4; A23 += up2(v4.y) * F4;
        A01 += up2(v5.x) * F5; A23 += up2(v5.y) * F5;
        A01 += up2(v6.x) * F6; A23 += up2(v6.y) * F6;
        A01 += up2(v7.x) * F7; A23 += up2(v7.y) * F7;
    }
    for (; j + 16 <= end; j += 16) {
        int s0 = ssrc[j + q];
        int s1 = ssrc[j + 4 + q];
        int s2 = ssrc[j + 8 + q];
        int s3 = ssrc[j + 12 + q];
        float f0 = dinv[s0], f1 = dinv[s1], f2 = dinv[s2], f3 = dinv[s3];
        uint2 v0 = h8[(size_t)s0 * 16 + l16];
        uint2 v1 = h8[(size_t)s1 * 16 + l16];
        uint2 v2 = h8[(size_t)s2 * 16 + l16];
        uint2 v3 = h8[(size_t)s3 * 16 + l16];
        f32x2 F0 = {f0, f0}, F1 = {f1, f1}, F2 = {f2, f2}, F3 = {f3, f3};
        A01 += up2(v0.x) * F0; A23 += up2(v0.y) * F0;
        A01 += up2(v1.x) * F1; A23 += up2(v1.y) * F1;
        A01 += up2(v2.x) * F2; A23 += up2(v2.y) * F2;
        A01 += up2(v3.x) * F3; A23 += up2(v3.y) * F3;
    }
    for (; j + 4 <= end; j += 4) {
        int s = ssrc[j + q];
        float f = dinv[s];
        uint2 v = h8[(size_t)s * 16 + l16];
        f32x2 F = {f, f};
        A01 += up2(v.x) * F; A23 += up2(v.y) * F;
    }
    unsigned rem = end - j;
    if ((unsigned)q < rem) {
        int s = ssrc[j + q];
        float f = dinv[s];
        uint2 v = h8[(size_t)s * 16 + l16];
        f32x2 F = {f, f};
        A01 += up2(v.x) * F; A23 += up2(v.y) * F;
    }
    float a0 = A01.x, a1 = A01.y, a2 = A23.x, a3 = A23.y;
    a0 += __shfl_xor(a0, 16); a0 += __shfl_xor(a0, 32);
    a1 += __shfl_xor(a1, 16); a1 += __shfl_xor(a1, 32);
    a2 += __shfl_xor(a2, 16); a2 += __shfl_xor(a2, 32);
    a3 += __shfl_xor(a3, 16); a3 += __shfl_xor(a3, 32);
    float4 bb = ((const float4*)b)[l16];
    float v0 = fmaxf(fmaf(a0, dn, bb.x), 0.f);
    float v1 = fmaxf(fmaf(a1, dn, bb.y), 0.f);
    float v2 = fmaxf(fmaf(a2, dn, bb.z), 0.f);
    float v3 = fmaxf(fmaf(a3, dn, bb.w), 0.f);
    float m = fmaxf(fmaxf(v0, v1), fmaxf(v2, v3));
    #pragma unroll
    for (int o = 8; o; o >>= 1) m = fmaxf(m, __shfl_xor(m, o));
    float sum = expf(v0 - m) + expf(v1 - m) + expf(v2 - m) + expf(v3 - m);
    #pragma unroll
    for (int o = 8; o; o >>= 1) sum += __shfl_xor(sum, o);
    float ls = logf(sum);
    if (q == 0) {
        float4 r;
        r.x = (v0 - m) - ls; r.y = (v1 - m) - ls;
        r.z = (v2 - m) - ls; r.w = (v3 - m) - ls;
        *(float4*)&out[(size_t)n * OUT_CH + l16 * 4] = r;
    }
}

// ---------------------------------------------------------------------------
// Fallback (atomic scatter) path, only if ws is too small for the CSR path.
__global__ __launch_bounds__(256) void deg_kernel(const int* __restrict__ ei32,
                                                  const long long* __restrict__ ei64,
                                                  const int* __restrict__ flag,
                                                  unsigned* __restrict__ deg) {
    const bool is64 = (*flag != 0);
    int i = blockIdx.x * blockDim.x + threadIdx.x;
    const int stride = gridDim.x * blockDim.x;
    for (; i < N_EDGES; i += stride) {
        int d = load_idx(ei32, ei64, is64, (long long)N_EDGES + i);
        atomicAdd(&deg[d], 1u);
    }
}

__global__ __launch_bounds__(256) void dinv_kernel(const unsigned* __restrict__ deg,
                                                   float* __restrict__ dinv) {
    int i = blockIdx.x * blockDim.x + threadIdx.x;
    if (i < N_NODES) dinv[i] = rsqrtf((float)(deg[i] + 1u));
}

__global__ __launch_bounds__(256) void scatter_kernel(const int* __restrict__ ei32,
                                                      const long long* __restrict__ ei64,
                                                      const int* __restrict__ flag,
                                                      const unsigned short* __restrict__ hs,
                                                      const float* __restrict__ dinv,
                                                      float* __restrict__ out) {
    const bool is64 = (*flag != 0);
    const int lane = threadIdx.x & 63;
    int w = blockIdx.x * (blockDim.x >> 6) + (threadIdx.x >> 6);
    const int nw = gridDim.x * (blockDim.x >> 6);
    for (int e = w; e < N_EDGES; e += nw) {
        int s = load_idx(ei32, ei64, is64, e);
        int d = load_idx(ei32, ei64, is64, (long long)N_EDGES + e);
        unsigned short us = hs[(size_t)s * OUT_CH + lane];
        float hv = __builtin_bit_cast(float, (unsigned)us << 16);
        atomicAdd(&out[(size_t)d * OUT_CH + lane], hv * dinv[s] * dinv[d]);
    }
}

__global__ __launch_bounds__(256) void final_kernel(const unsigned short* __restrict__ hs,
                                                    const float* __restrict__ dinv,
                                                    const float* __restrict__ b,
                                                    float* __restrict__ out) {
    const int lane = threadIdx.x & 63;
    int w = blockIdx.x * (blockDim.x >> 6) + (threadIdx.x >> 6);
    const int nw = gridDim.x * (blockDim.x >> 6);
    const float bias = b[lane];
    for (int n = w; n < N_NODES; n += nw) {
        float di = dinv[n];
        unsigned short us = hs[(size_t)n * OUT_CH + lane];
        float hv = __builtin_bit_cast(float, (unsigned)us << 16);
        float v = out[(size_t)n * OUT_CH + lane] + hv * di * di + bias;
        v = fmaxf(v, 0.f);
        float m = v;
        #pragma unroll
        for (int o = 32; o; o >>= 1) m = fmaxf(m, __shfl_xor(m, o));
        float ex = expf(v - m);
        float sum = ex;
        #pragma unroll
        for (int o = 32; o; o >>= 1) sum += __shfl_xor(sum, o);
        out[(size_t)n * OUT_CH + lane] = (v - m) - logf(sum);
    }
}

// ---------------------------------------------------------------------------
extern "C" void kernel_launch(void* const* d_in, const int* in_sizes, int n_in,
                              void* d_out, int out_size, void* d_ws, size_t ws_size,
                              hipStream_t stream) {
    const float* x  = (const float*)d_in[0];
    const void*  ei = d_in[1];
    const float* W  = (const float*)d_in[2];
    const float* b  = (const float*)d_in[3];
    float* out = (float*)d_out;

    char* ws = (char*)d_ws;
    int* flag = (int*)(ws + WS_FLAG_OFF);
    unsigned* gcnt = (unsigned*)(ws + WS_GCNT_OFF);

    const int* ei32       = (const int*)ei;
    const long long* ei64 = (const long long*)ei;

    probe_kernel<<<1, 64, 0, stream>>>((const unsigned*)ei, flag, gcnt);

    if (ws_size >= (size_t)WS_NEED) {
        float*    dinv = (float*)(ws + WS_DINV_OFF);
        uint2*    nse  = (uint2*)(ws + WS_NSE_OFF);
        unsigned* edg  = (unsigned*)(ws + WS_EDG_OFF);
        unsigned short* hs = (unsigned short*)(ws + WS_H_OFF);

        partition_kernel<<<NBLK_PART, 512, 0, stream>>>(ei32, ei64, flag, gcnt, edg);
        sortgemm_kernel<<<K_BKT + NBLK_GEMM, 256, 0, stream>>>(
            edg, gcnt, nse, dinv, x, W, hs);
        reduce_kernel<<<(N_NODES + 3) / 4, 256, 0, stream>>>(
            hs, dinv, nse, (const int*)edg, b, out);
    } else {
        unsigned* deg  = (unsigned*)(ws + WSF_DEG_OFF);
        float*    dinv = (float*)(ws + WSF_DINV_OFF);
        unsigned short* hs = (unsigned short*)(ws + WSF_H_OFF);
        hipMemsetAsync(deg, 0, (size_t)N_NODES * sizeof(unsigned), stream);
        hipMemsetAsync(d_out, 0, (size_t)out_size * sizeof(float), stream);
        deg_kernel<<<2048, 256, 0, stream>>>(ei32, ei64, flag, deg);
        dinv_kernel<<<(N_NODES + 255) / 256, 256, 0, stream>>>(deg, dinv);
        gemm_only_kernel<<<NBLK_GEMM, 256, 0, stream>>>(x, W, hs);
        scatter_kernel<<<2048, 256, 0, stream>>>(ei32, ei64, flag, hs, dinv, out);
        final_kernel<<<1024, 256, 0, stream>>>(hs, dinv, b, out);
    }
}

// Round 16
// 149.276 us; speedup vs baseline: 1.1557x; 1.0574x over previous
//
#include <hip/hip_runtime.h>
#include <cstddef>
#include <cstdint>

#define N_NODES 100000
#define IN_CH 256
#define OUT_CH 64
#define N_EDGES 3200000

// bucketing: 128 nodes per bucket, fixed-capacity slots
#define BKT_SHIFT 7
#define BKT_R     128
#define K_BKT     782                 // ceil(100000/128)
#define BKT_CAP   6144                // mean 4096 + 32 sigma; slots of 24KB
#define T_PART    8192                // edges per partition block
#define NBLK_PART ((N_EDGES + T_PART - 1) / T_PART)   // 391
#define NBLK_GEMM 512
#define N_TILES   (N_NODES / 16)      // 6250

// ---- ws layout (bytes) ----
#define WS_FLAG_OFF   0
#define WS_GCNT_OFF   64              // 782 u32 bucket fill counts
#define WS_DINV_OFF   4096            // 400000 B
#define WS_NSE_OFF    404096          // 100000 uint2 = 800000 B
#define WS_EDG_OFF    1204224         // 782*6144*4 = 19,218,432 B (pairs -> sorted src)
#define WS_H_OFF      20422656        // bf16 h: 100000*64*2 = 12.8MB (unscaled)
#define WS_NEED       33222656

// ---- fallback (atomic) layout ----
#define WSF_DEG_OFF   4096
#define WSF_DINV_OFF  404096
#define WSF_H_OFF     804096

typedef __attribute__((ext_vector_type(8))) short bshort8;
typedef __attribute__((ext_vector_type(4))) float f32x4;
typedef __attribute__((ext_vector_type(2))) float f32x2;
typedef __attribute__((ext_vector_type(4))) unsigned u32x4;

// ---------------------------------------------------------------------------
static __device__ __forceinline__ unsigned short f2bf(float f) {
    unsigned u = __builtin_bit_cast(unsigned, f);
    u += 0x7FFFu + ((u >> 16) & 1u);     // RNE (finite inputs)
    return (unsigned short)(u >> 16);
}
static __device__ __forceinline__ float bflo(unsigned u) {
    return __builtin_bit_cast(float, u << 16);
}
static __device__ __forceinline__ float bfhi(unsigned u) {
    return __builtin_bit_cast(float, u & 0xFFFF0000u);
}
static __device__ __forceinline__ f32x2 up2(unsigned u) {
    f32x2 r;
    r.x = __builtin_bit_cast(float, u << 16);
    r.y = __builtin_bit_cast(float, u & 0xFFFF0000u);
    return r;
}

// ---------------------------------------------------------------------------
// probe: detect int64 vs int32 edge layout AND zero the gcnt counters.
__global__ void probe_kernel(const unsigned* __restrict__ ei, int* __restrict__ flag,
                             unsigned* __restrict__ gcnt) {
    if (blockIdx.x == 0) {
        for (int k = threadIdx.x; k < K_BKT; k += 64) gcnt[k] = 0u;
        if (threadIdx.x == 0) {
            int all0 = 1;
            for (int i = 0; i < 16; ++i) all0 &= (ei[2 * i + 1] == 0u);
            *flag = all0;  // 1 => int64 layout, 0 => int32 layout
        }
    }
}

__device__ __forceinline__ int load_idx(const int* ei32, const long long* ei64,
                                        bool is64, long long pos) {
    return is64 ? (int)ei64[pos] : ei32[pos];
}

// ---------------------------------------------------------------------------
// Shared gemm body (256 threads, 4 waves): h = x @ W, bf16 store, UNSCALED.
// (round-9..15-proven code, unchanged)
static __device__ __forceinline__ void gemm_body(char* smem, int gbid, int nblk,
                                                 const float* __restrict__ x,
                                                 const float* __restrict__ W,
                                                 unsigned short* __restrict__ hs) {
    unsigned short (*Wf)[4][64][8] = (unsigned short (*)[4][64][8])smem;
    const int tid = threadIdx.x;
    const int lane = tid & 63;
    const int wv = tid >> 6;           // 4 waves

    for (int i = tid; i < 8 * 4 * 64 * 8; i += 256) {
        int kt = i >> 11;
        int rem = i & 2047;
        int ct = rem >> 9;
        int rem2 = rem & 511;
        int l = rem2 >> 3;
        int j = rem2 & 7;
        int kk = kt * 32 + (l >> 4) * 8 + j;
        int cc = ct * 16 + (l & 15);
        ((unsigned short*)Wf)[i] = f2bf(W[(size_t)kk * OUT_CH + cc]);
    }
    __syncthreads();

    const int r16 = lane & 15;   // A row within tile
    const int q = lane >> 4;     // k-quarter (A), row-quarter (C)

    for (int t = gbid * 4 + wv; t < N_TILES; t += nblk * 4) {
        const int row0 = t * 16;
        const float* xrow = &x[(size_t)(row0 + r16) * IN_CH + q * 8];
        f32x4 acc[4] = {{0.f,0.f,0.f,0.f},{0.f,0.f,0.f,0.f},
                        {0.f,0.f,0.f,0.f},{0.f,0.f,0.f,0.f}};
        #pragma unroll
        for (int kt = 0; kt < 8; ++kt) {
            float4 x0 = *(const float4*)&xrow[kt * 32];
            float4 x1 = *(const float4*)&xrow[kt * 32 + 4];
            unsigned p0, p1, p2, p3;
            asm("v_cvt_pk_bf16_f32 %0, %1, %2" : "=v"(p0) : "v"(x0.x), "v"(x0.y));
            asm("v_cvt_pk_bf16_f32 %0, %1, %2" : "=v"(p1) : "v"(x0.z), "v"(x0.w));
            asm("v_cvt_pk_bf16_f32 %0, %1, %2" : "=v"(p2) : "v"(x1.x), "v"(x1.y));
            asm("v_cvt_pk_bf16_f32 %0, %1, %2" : "=v"(p3) : "v"(x1.z), "v"(x1.w));
            u32x4 au = {p0, p1, p2, p3};
            bshort8 af = __builtin_bit_cast(bshort8, au);
            #pragma unroll
            for (int ct = 0; ct < 4; ++ct) {
                bshort8 bf = *(const bshort8*)&Wf[kt][ct][lane][0];
                acc[ct] = __builtin_amdgcn_mfma_f32_16x16x32_bf16(af, bf, acc[ct], 0, 0, 0);
            }
        }
        #pragma unroll
        for (int ct = 0; ct < 4; ++ct) {
            #pragma unroll
            for (int r = 0; r < 4; ++r) {
                int row = row0 + q * 4 + r;
                hs[(size_t)row * OUT_CH + ct * 16 + r16] = f2bf(acc[ct][r]);
            }
        }
    }
}

// ---------------------------------------------------------------------------
// Partition with block-level LDS counting sort (round-15) + j->bucket LUT
// drain (replaces the 10-probe binary search with 1 independent LDS read).
// Occupancy note: only 391 blocks over 256 CUs (~1.5/CU), so the extra 16KB
// LDS (58.5KB total, 2 blocks/CU cap) is free.
__global__ __launch_bounds__(512) void partition_kernel(const int* __restrict__ ei32,
                                                        const long long* __restrict__ ei64,
                                                        const int* __restrict__ flag,
                                                        unsigned* __restrict__ gcnt,
                                                        unsigned* __restrict__ edg) {
    __shared__ unsigned ordered[T_PART];      // 32 KB
    __shared__ unsigned short lut[T_PART];    // 16 KB: slot j -> bucket k
    __shared__ unsigned hist[K_BKT];          // counts -> then global run base
    __shared__ unsigned scan[K_BKT + 1];      // block-local exclusive scan
    __shared__ unsigned cur[K_BKT];           // running rank cursor
    const bool is64 = (*flag != 0);
    const int tid = threadIdx.x;
    const int lane = tid & 63;
    const int start = blockIdx.x * T_PART;
    const int end   = min(start + T_PART, N_EDGES);
    const int total = end - start;
    const int pbase = start >> 1;
    const int pend  = end >> 1;
    unsigned dcx[8], dcy[8];

    for (int k = tid; k < K_BKT; k += 512) hist[k] = 0u;
    __syncthreads();
    // pass 1: histogram + register-cache dst ids
    if (is64) {
        const longlong2* d2 = (const longlong2*)&ei64[N_EDGES];
        #pragma unroll
        for (int it = 0; it < 8; ++it) {
            int i = pbase + it * 512 + tid;
            if (i < pend) {
                longlong2 d = d2[i];
                dcx[it] = (unsigned)(int)d.x;
                dcy[it] = (unsigned)(int)d.y;
                atomicAdd(&hist[dcx[it] >> BKT_SHIFT], 1u);
                atomicAdd(&hist[dcy[it] >> BKT_SHIFT], 1u);
            }
        }
    } else {
        const int2* d2 = (const int2*)&ei32[N_EDGES];
        #pragma unroll
        for (int it = 0; it < 8; ++it) {
            int i = pbase + it * 512 + tid;
            if (i < pend) {
                int2 d = d2[i];
                dcx[it] = (unsigned)d.x;
                dcy[it] = (unsigned)d.y;
                atomicAdd(&hist[dcx[it] >> BKT_SHIFT], 1u);
                atomicAdd(&hist[dcy[it] >> BKT_SHIFT], 1u);
            }
        }
    }
    __syncthreads();
    // wave-0 chunked shfl scan of hist -> scan[1..K_BKT], scan[0]=0
    if (tid < 64) {
        if (tid == 0) scan[0] = 0u;
        unsigned run = 0u;
        for (int c0 = 0; c0 < K_BKT; c0 += 64) {
            int k = c0 + lane;
            unsigned v = (k < K_BKT) ? hist[k] : 0u;
            unsigned incl = v;
            #pragma unroll
            for (int d = 1; d < 64; d <<= 1) {
                unsigned tq = __shfl_up(incl, d);
                if (lane >= d) incl += tq;
            }
            if (k < K_BKT) scan[k + 1] = run + incl;
            run += __shfl(incl, 63);
        }
    }
    __syncthreads();
    // reservation (hist[k] <- global run base) + cursor init + LUT fill
    for (int k = tid; k < K_BKT; k += 512) {
        unsigned c = hist[k];
        unsigned base = c ? atomicAdd(&gcnt[k], c) : 0u;
        hist[k] = base + (unsigned)k * BKT_CAP;
        unsigned s0 = scan[k];
        cur[k] = s0;
        for (unsigned j = s0; j < s0 + c; ++j) lut[j] = (unsigned short)k;
    }
    __syncthreads();
    // pass 2: read src stream, rank-scatter pairs into LDS ordered[]
    if (is64) {
        const longlong2* s2 = (const longlong2*)&ei64[0];
        #pragma unroll
        for (int it = 0; it < 8; ++it) {
            int i = pbase + it * 512 + tid;
            if (i < pend) {
                longlong2 s = s2[i];
                unsigned dx = dcx[it], dy = dcy[it];
                unsigned p0 = atomicAdd(&cur[dx >> BKT_SHIFT], 1u);
                ordered[p0] = (unsigned)s.x | ((dx & (BKT_R - 1)) << 17);
                unsigned p1 = atomicAdd(&cur[dy >> BKT_SHIFT], 1u);
                ordered[p1] = (unsigned)s.y | ((dy & (BKT_R - 1)) << 17);
            }
        }
    } else {
        const int2* s2 = (const int2*)&ei32[0];
        #pragma unroll
        for (int it = 0; it < 8; ++it) {
            int i = pbase + it * 512 + tid;
            if (i < pend) {
                int2 s = s2[i];
                unsigned dx = dcx[it], dy = dcy[it];
                unsigned p0 = atomicAdd(&cur[dx >> BKT_SHIFT], 1u);
                ordered[p0] = (unsigned)s.x | ((dx & (BKT_R - 1)) << 17);
                unsigned p1 = atomicAdd(&cur[dy >> BKT_SHIFT], 1u);
                ordered[p1] = (unsigned)s.y | ((dy & (BKT_R - 1)) << 17);
            }
        }
    }
    __syncthreads();
    // pass 3: drain in sorted order; adjacent lanes -> adjacent global addrs.
    for (int j = tid; j < total; j += 512) {
        unsigned pr = ordered[j];
        int k = lut[j];
        edg[hist[k] + ((unsigned)j - scan[k])] = pr;
    }
}

// ---------------------------------------------------------------------------
// FUSED sort2 + gemm (round-11..15-proven): blocks [0, K_BKT) counting-sort
// their bucket (LDS-staged, in place -> nse/dinv); blocks [K_BKT, +NBLK_GEMM)
// gemm.
__global__ __launch_bounds__(256) void sortgemm_kernel(unsigned* __restrict__ edg,
                                                       const unsigned* __restrict__ gcnt,
                                                       uint2* __restrict__ nse,
                                                       float* __restrict__ dinv,
                                                       const float* __restrict__ x,
                                                       const float* __restrict__ W,
                                                       unsigned short* __restrict__ hs) {
    __shared__ char smem[32768];
    const int bid = blockIdx.x;
    if (bid < K_BKT) {
        unsigned* ld   = (unsigned*)smem;            // 24576 B
        unsigned* hist = (unsigned*)(smem + 24576);  // 512 B
        unsigned* cur  = (unsigned*)(smem + 25088);  // 512 B
        const int k = bid;
        const int t = threadIdx.x;
        const unsigned cnt = min(gcnt[k], (unsigned)BKT_CAP);
        const unsigned base = (unsigned)k * BKT_CAP;

        for (unsigned j = t; j < cnt; j += 256) ld[j] = edg[base + j];
        if (t < BKT_R) hist[t] = 0u;
        __syncthreads();
        for (unsigned j = t; j < cnt; j += 256)
            atomicAdd(&hist[ld[j] >> 17], 1u);
        __syncthreads();
        if (t < BKT_R) cur[t] = hist[t];
        __syncthreads();
        #pragma unroll
        for (int d = 1; d < BKT_R; d <<= 1) {
            unsigned v = (t < BKT_R && t >= d) ? cur[t - d] : 0u;
            __syncthreads();
            if (t < BKT_R) cur[t] += v;
            __syncthreads();
        }
        if (t < BKT_R) {
            unsigned mydeg = hist[t];
            unsigned start = base + cur[t] - mydeg;   // exclusive, padded coords
            int n = k * BKT_R + t;
            if (n < N_NODES) {
                nse[n] = make_uint2(start, start + mydeg);
                dinv[n] = rsqrtf((float)(mydeg + 1u));
            }
            cur[t] = start;
        }
        __syncthreads();
        for (unsigned j = t; j < cnt; j += 256) {
            unsigned p = ld[j];
            unsigned pos = atomicAdd(&cur[p >> 17], 1u);
            edg[pos] = p & 0x1FFFF;     // sorted src id
        }
    } else {
        gemm_body(smem, bid - K_BKT, NBLK_GEMM, x, W, hs);
    }
}

// gemm-only wrapper (fallback path)
__global__ __launch_bounds__(256) void gemm_only_kernel(const float* __restrict__ x,
                                                        const float* __restrict__ W,
                                                        unsigned short* __restrict__ hs) {
    __shared__ char smem[32768];
    gemm_body(smem, blockIdx.x, gridDim.x, x, W, hs);
}

// ---------------------------------------------------------------------------
// Wave per node, quarter-wave per edge, 32/16/4/1 edge loops (round-13 code;
// reduce is at its measured structural floor ~78-79us).
__global__ __launch_bounds__(256) void reduce_kernel(const unsigned short* __restrict__ hs,
                                                     const float* __restrict__ dinv,
                                                     const uint2* __restrict__ nse,
                                                     const int* __restrict__ ssrc,
                                                     const float* __restrict__ b,
                                                     float* __restrict__ out) {
    const int n = blockIdx.x * 4 + (threadIdx.x >> 6);
    const int lane = threadIdx.x & 63;
    const int q = lane >> 4;
    const int l16 = lane & 15;
    if (n >= N_NODES) return;
    const uint2* h8 = (const uint2*)hs;   // one row = 16 uint2
    const float dn = dinv[n];
    f32x2 A01 = {0.f, 0.f}, A23 = {0.f, 0.f};
    {   // self-loop: h[n]*dinv[n]; counted once (q==0)
        uint2 sv = h8[(size_t)n * 16 + l16];
        if (q == 0) {
            f32x2 dnv = {dn, dn};
            A01 = up2(sv.x) * dnv;
            A23 = up2(sv.y) * dnv;
        }
    }
    uint2 se = nse[n];
    unsigned j = se.x;
    const unsigned end = se.y;
    for (; j + 32 <= end; j += 32) {
        int s0 = ssrc[j + q];
        int s1 = ssrc[j + 4 + q];
        int s2 = ssrc[j + 8 + q];
        int s3 = ssrc[j + 12 + q];
        int s4 = ssrc[j + 16 + q];
        int s5 = ssrc[j + 20 + q];
        int s6 = ssrc[j + 24 + q];
        int s7 = ssrc[j + 28 + q];
        float f0 = dinv[s0], f1 = dinv[s1], f2 = dinv[s2], f3 = dinv[s3];
        float f4 = dinv[s4], f5 = dinv[s5], f6 = dinv[s6], f7 = dinv[s7];
        uint2 v0 = h8[(size_t)s0 * 16 + l16];
        uint2 v1 = h8[(size_t)s1 * 16 + l16];
        uint2 v2 = h8[(size_t)s2 * 16 + l16];
        uint2 v3 = h8[(size_t)s3 * 16 + l16];
        uint2 v4 = h8[(size_t)s4 * 16 + l16];
        uint2 v5 = h8[(size_t)s5 * 16 + l16];
        uint2 v6 = h8[(size_t)s6 * 16 + l16];
        uint2 v7 = h8[(size_t)s7 * 16 + l16];
        f32x2 F0 = {f0, f0}, F1 = {f1, f1}, F2 = {f2, f2}, F3 = {f3, f3};
        f32x2 F4 = {f4, f4}, F5 = {f5, f5}, F6 = {f6, f6}, F7 = {f7, f7};
        A01 += up2(v0.x) * F0; A23 += up2(v0.y) * F0;
        A01 += up2(v1.x) * F1; A23 += up2(v1.y) * F1;
        A01 += up2(v2.x) * F2; A23 += up2(v2.y) * F2;
        A01 += up2(v3.x) * F3; A23 += up2(v3.y) * F3;
        A01 += up2(v4.x) * F4; A23 += up2(v4.y) * F4;
        A01 += up2(v5.x) * F5; A23 += up2(v5.y) * F5;
        A01 += up2(v6.x) * F6; A23 += up2(v6.y) * F6;
        A01 += up2(v7.x) * F7; A23 += up2(v7.y) * F7;
    }
    for (; j + 16 <= end; j += 16) {
        int s0 = ssrc[j + q];
        int s1 = ssrc[j + 4 + q];
        int s2 = ssrc[j + 8 + q];
        int s3 = ssrc[j + 12 + q];
        float f0 = dinv[s0], f1 = dinv[s1], f2 = dinv[s2], f3 = dinv[s3];
        uint2 v0 = h8[(size_t)s0 * 16 + l16];
        uint2 v1 = h8[(size_t)s1 * 16 + l16];
        uint2 v2 = h8[(size_t)s2 * 16 + l16];
        uint2 v3 = h8[(size_t)s3 * 16 + l16];
        f32x2 F0 = {f0, f0}, F1 = {f1, f1}, F2 = {f2, f2}, F3 = {f3, f3};
        A01 += up2(v0.x) * F0; A23 += up2(v0.y) * F0;
        A01 += up2(v1.x) * F1; A23 += up2(v1.y) * F1;
        A01 += up2(v2.x) * F2; A23 += up2(v2.y) * F2;
        A01 += up2(v3.x) * F3; A23 += up2(v3.y) * F3;
    }
    for (; j + 4 <= end; j += 4) {
        int s = ssrc[j + q];
        float f = dinv[s];
        uint2 v = h8[(size_t)s * 16 + l16];
        f32x2 F = {f, f};
        A01 += up2(v.x) * F; A23 += up2(v.y) * F;
    }
    unsigned rem = end - j;
    if ((unsigned)q < rem) {
        int s = ssrc[j + q];
        float f = dinv[s];
        uint2 v = h8[(size_t)s * 16 + l16];
        f32x2 F = {f, f};
        A01 += up2(v.x) * F; A23 += up2(v.y) * F;
    }
    float a0 = A01.x, a1 = A01.y, a2 = A23.x, a3 = A23.y;
    a0 += __shfl_xor(a0, 16); a0 += __shfl_xor(a0, 32);
    a1 += __shfl_xor(a1, 16); a1 += __shfl_xor(a1, 32);
    a2 += __shfl_xor(a2, 16); a2 += __shfl_xor(a2, 32);
    a3 += __shfl_xor(a3, 16); a3 += __shfl_xor(a3, 32);
    float4 bb = ((const float4*)b)[l16];
    float v0 = fmaxf(fmaf(a0, dn, bb.x), 0.f);
    float v1 = fmaxf(fmaf(a1, dn, bb.y), 0.f);
    float v2 = fmaxf(fmaf(a2, dn, bb.z), 0.f);
    float v3 = fmaxf(fmaf(a3, dn, bb.w), 0.f);
    float m = fmaxf(fmaxf(v0, v1), fmaxf(v2, v3));
    #pragma unroll
    for (int o = 8; o; o >>= 1) m = fmaxf(m, __shfl_xor(m, o));
    float sum = expf(v0 - m) + expf(v1 - m) + expf(v2 - m) + expf(v3 - m);
    #pragma unroll
    for (int o = 8; o; o >>= 1) sum += __shfl_xor(sum, o);
    float ls = logf(sum);
    if (q == 0) {
        float4 r;
        r.x = (v0 - m) - ls; r.y = (v1 - m) - ls;
        r.z = (v2 - m) - ls; r.w = (v3 - m) - ls;
        *(float4*)&out[(size_t)n * OUT_CH + l16 * 4] = r;
    }
}

// ---------------------------------------------------------------------------
// Fallback (atomic scatter) path, only if ws is too small for the CSR path.
__global__ __launch_bounds__(256) void deg_kernel(const int* __restrict__ ei32,
                                                  const long long* __restrict__ ei64,
                                                  const int* __restrict__ flag,
                                                  unsigned* __restrict__ deg) {
    const bool is64 = (*flag != 0);
    int i = blockIdx.x * blockDim.x + threadIdx.x;
    const int stride = gridDim.x * blockDim.x;
    for (; i < N_EDGES; i += stride) {
        int d = load_idx(ei32, ei64, is64, (long long)N_EDGES + i);
        atomicAdd(&deg[d], 1u);
    }
}

__global__ __launch_bounds__(256) void dinv_kernel(const unsigned* __restrict__ deg,
                                                   float* __restrict__ dinv) {
    int i = blockIdx.x * blockDim.x + threadIdx.x;
    if (i < N_NODES) dinv[i] = rsqrtf((float)(deg[i] + 1u));
}

__global__ __launch_bounds__(256) void scatter_kernel(const int* __restrict__ ei32,
                                                      const long long* __restrict__ ei64,
                                                      const int* __restrict__ flag,
                                                      const unsigned short* __restrict__ hs,
                                                      const float* __restrict__ dinv,
                                                      float* __restrict__ out) {
    const bool is64 = (*flag != 0);
    const int lane = threadIdx.x & 63;
    int w = blockIdx.x * (blockDim.x >> 6) + (threadIdx.x >> 6);
    const int nw = gridDim.x * (blockDim.x >> 6);
    for (int e = w; e < N_EDGES; e += nw) {
        int s = load_idx(ei32, ei64, is64, e);
        int d = load_idx(ei32, ei64, is64, (long long)N_EDGES + e);
        unsigned short us = hs[(size_t)s * OUT_CH + lane];
        float hv = __builtin_bit_cast(float, (unsigned)us << 16);
        atomicAdd(&out[(size_t)d * OUT_CH + lane], hv * dinv[s] * dinv[d]);
    }
}

__global__ __launch_bounds__(256) void final_kernel(const unsigned short* __restrict__ hs,
                                                    const float* __restrict__ dinv,
                                                    const float* __restrict__ b,
                                                    float* __restrict__ out) {
    const int lane = threadIdx.x & 63;
    int w = blockIdx.x * (blockDim.x >> 6) + (threadIdx.x >> 6);
    const int nw = gridDim.x * (blockDim.x >> 6);
    const float bias = b[lane];
    for (int n = w; n < N_NODES; n += nw) {
        float di = dinv[n];
        unsigned short us = hs[(size_t)n * OUT_CH + lane];
        float hv = __builtin_bit_cast(float, (unsigned)us << 16);
        float v = out[(size_t)n * OUT_CH + lane] + hv * di * di + bias;
        v = fmaxf(v, 0.f);
        float m = v;
        #pragma unroll
        for (int o = 32; o; o >>= 1) m = fmaxf(m, __shfl_xor(m, o));
        float ex = expf(v - m);
        float sum = ex;
        #pragma unroll
        for (int o = 32; o; o >>= 1) sum += __shfl_xor(sum, o);
        out[(size_t)n * OUT_CH + lane] = (v - m) - logf(sum);
    }
}

// ---------------------------------------------------------------------------
extern "C" void kernel_launch(void* const* d_in, const int* in_sizes, int n_in,
                              void* d_out, int out_size, void* d_ws, size_t ws_size,
                              hipStream_t stream) {
    const float* x  = (const float*)d_in[0];
    const void*  ei = d_in[1];
    const float* W  = (const float*)d_in[2];
    const float* b  = (const float*)d_in[3];
    float* out = (float*)d_out;

    char* ws = (char*)d_ws;
    int* flag = (int*)(ws + WS_FLAG_OFF);
    unsigned* gcnt = (unsigned*)(ws + WS_GCNT_OFF);

    const int* ei32       = (const int*)ei;
    const long long* ei64 = (const long long*)ei;

    probe_kernel<<<1, 64, 0, stream>>>((const unsigned*)ei, flag, gcnt);

    if (ws_size >= (size_t)WS_NEED) {
        float*    dinv = (float*)(ws + WS_DINV_OFF);
        uint2*    nse  = (uint2*)(ws + WS_NSE_OFF);
        unsigned* edg  = (unsigned*)(ws + WS_EDG_OFF);
        unsigned short* hs = (unsigned short*)(ws + WS_H_OFF);

        partition_kernel<<<NBLK_PART, 512, 0, stream>>>(ei32, ei64, flag, gcnt, edg);
        sortgemm_kernel<<<K_BKT + NBLK_GEMM, 256, 0, stream>>>(
            edg, gcnt, nse, dinv, x, W, hs);
        reduce_kernel<<<(N_NODES + 3) / 4, 256, 0, stream>>>(
            hs, dinv, nse, (const int*)edg, b, out);
    } else {
        unsigned* deg  = (unsigned*)(ws + WSF_DEG_OFF);
        float*    dinv = (float*)(ws + WSF_DINV_OFF);
        unsigned short* hs = (unsigned short*)(ws + WSF_H_OFF);
        hipMemsetAsync(deg, 0, (size_t)N_NODES * sizeof(unsigned), stream);
        hipMemsetAsync(d_out, 0, (size_t)out_size * sizeof(float), stream);
        deg_kernel<<<2048, 256, 0, stream>>>(ei32, ei64, flag, deg);
        dinv_kernel<<<(N_NODES + 255) / 256, 256, 0, stream>>>(deg, dinv);
        gemm_only_kernel<<<NBLK_GEMM, 256, 0, stream>>>(x, W, hs);
        scatter_kernel<<<2048, 256, 0, stream>>>(ei32, ei64, flag, hs, dinv, out);
        final_kernel<<<1024, 256, 0, stream>>>(hs, dinv, b, out);
    }
}